// Round 6
// baseline (1047.063 us; speedup 1.0000x reference)
//
#include <hip/hip_runtime.h>
#include <math.h>

#define NN   100000
#define EE   800000
#define RR   6
#define BB   1000
#define HH   128
#define MM   (RR*NN)
#define NBPR ((NN + 255) >> 8)
#define NBK  (RR * NBPR)
#define CH   4096

static inline int ceil_div(int a, int b){ return (a+b-1)/b; }

typedef __attribute__((ext_vector_type(8))) short bf16x8;
typedef __attribute__((ext_vector_type(4))) short bf16x4;
typedef __attribute__((ext_vector_type(4))) float f32x4;

__device__ __forceinline__ unsigned fenc(float f){
  unsigned u = __float_as_uint(f);
  return (u & 0x80000000u) ? ~u : (u | 0x80000000u);
}
__device__ __forceinline__ float fdec(unsigned u){
  return __uint_as_float((u & 0x80000000u) ? (u & 0x7fffffffu) : ~u);
}
__device__ __forceinline__ unsigned short f2bf(float f){
  unsigned u = __float_as_uint(f);
  return (unsigned short)((u + 0x7fffu + ((u >> 16) & 1u)) >> 16);
}
__device__ __forceinline__ float bf2f(unsigned short h){
  return __uint_as_float(((unsigned)h) << 16);
}

// ================= bucketed CSR build (unchanged, proven) =================
__global__ void k_bcount(const int* __restrict__ edges, int* __restrict__ bcnt)
{
  __shared__ int hist[NBPR];
  int t = threadIdx.x;
  const int nch = (EE + CH - 1) / CH;
  int r = blockIdx.x / nch, c = blockIdx.x - r*nch;
  for (int i = t; i < NBPR; i += 256) hist[i] = 0;
  __syncthreads();
  const int* dptr = edges + (size_t)r*2*EE + EE;
  int e0 = c*CH, e1 = min(EE, e0 + CH);
  for (int i = e0 + t; i < e1; i += 256)
    atomicAdd(&hist[dptr[i] >> 8], 1);
  __syncthreads();
  for (int i = t; i < NBPR; i += 256) {
    int h = hist[i];
    if (h) atomicAdd(&bcnt[r*NBPR + i], h);
  }
}

__global__ void k_bscan(const int* __restrict__ bcnt, int* __restrict__ boff,
                        int* __restrict__ off)
{
  __shared__ int sh[256];
  int t = threadIdx.x;
  int carry = 0;
  for (int c = 0; c < NBK; c += 256) {
    int idx = c + t;
    int v = (idx < NBK) ? bcnt[idx] : 0;
    sh[t] = v;
    __syncthreads();
    for (int o = 1; o < 256; o <<= 1) {
      int add = (t >= o) ? sh[t-o] : 0;
      __syncthreads();
      sh[t] += add;
      __syncthreads();
    }
    int incl = sh[t];
    int tot  = sh[255];
    if (idx < NBK) boff[idx] = carry + incl - v;
    __syncthreads();
    carry += tot;
  }
  if (t == 0) { boff[NBK] = carry; off[MM] = carry; }
}

__global__ void k_binscatter(const int* __restrict__ edges, int* __restrict__ bcur,
                             unsigned* __restrict__ ebkt)
{
  __shared__ int hist[NBPR];
  __shared__ int base[NBPR];
  int t = threadIdx.x;
  const int nch = (EE + CH - 1) / CH;
  int r = blockIdx.x / nch, c = blockIdx.x - r*nch;
  for (int i = t; i < NBPR; i += 256) hist[i] = 0;
  __syncthreads();
  const int* sptr = edges + (size_t)r*2*EE;
  const int* dptr = sptr + EE;
  int e0 = c*CH, e1 = min(EE, e0 + CH);
  for (int i = e0 + t; i < e1; i += 256)
    atomicAdd(&hist[dptr[i] >> 8], 1);
  __syncthreads();
  for (int i = t; i < NBPR; i += 256) {
    int h = hist[i];
    base[i] = h ? atomicAdd(&bcur[r*NBPR + i], h) : 0;
    hist[i] = 0;
  }
  __syncthreads();
  for (int i = e0 + t; i < e1; i += 256) {
    int dst = dptr[i];
    int b = dst >> 8;
    int slot = base[b] + atomicAdd(&hist[b], 1);
    ebkt[slot] = ((unsigned)sptr[i] << 8) | (unsigned)(dst & 255);
  }
}

__global__ void k_bbuild(const unsigned* __restrict__ ebkt, const int* __restrict__ boff,
                         int* __restrict__ off, int* __restrict__ elist)
{
  __shared__ int cnt[256];
  __shared__ int sc[256];
  __shared__ int cur[256];
  int t = threadIdx.x;
  int bb = blockIdx.x;
  int e0 = boff[bb], e1 = boff[bb+1];
  cnt[t] = 0;
  __syncthreads();
  for (int i = e0 + t; i < e1; i += 256)
    atomicAdd(&cnt[ebkt[i] & 255u], 1);
  __syncthreads();
  sc[t] = cnt[t];
  __syncthreads();
  for (int o = 1; o < 256; o <<= 1) {
    int add = (t >= o) ? sc[t-o] : 0;
    __syncthreads();
    sc[t] += add;
    __syncthreads();
  }
  int excl = sc[t] - cnt[t];
  int r = bb / NBPR, b = bb - r*NBPR;
  int dst = b*256 + t;
  if (dst < NN) off[r*NN + dst] = e0 + excl;
  cur[t] = e0 + excl;
  __syncthreads();
  for (int i = e0 + t; i < e1; i += 256) {
    unsigned w = ebkt[i];
    int slot = atomicAdd(&cur[w & 255u], 1);
    elist[slot] = (int)(w >> 8);
  }
}

// ================= feature prep (bf16 hi/lo planes, K padded 21->32) =================
__global__ void k_featprep(const float* __restrict__ x_all, const float* __restrict__ pos_table,
                           short* __restrict__ x0h, short* __restrict__ x0l)
{
  int gid = blockIdx.x*256 + threadIdx.x;
  if (gid >= NN*32) return;
  int nidx = gid >> 5, c = gid & 31;
  float v = 0.f;
  if (c < 13) {
    int scl = (c < 5) ? c : c + 1;
    v = x_all[nidx*14 + scl];
  } else if (c < 21) {
    int pi = (int)x_all[nidx*14 + 5];
    pi = pi < 0 ? 0 : (pi > 23 ? 23 : pi);
    v = pos_table[pi*8 + (c - 13)];
  }
  unsigned short h = f2bf(v);
  unsigned short l = f2bf(v - bf2f(h));
  x0h[gid] = (short)h;
  x0l[gid] = (short)l;
}

// ================= weight prep: W[r][k][128] f32 -> Wt[r][out=128][KP] bf16 hi/lo ======
template<int KP>
__global__ void k_wprep(const float* __restrict__ W, int K,
                        short* __restrict__ Wh, short* __restrict__ Wl)
{
  int gid = blockIdx.x*256 + threadIdx.x;
  if (gid >= RR*128*KP) return;
  int r = gid / (128*KP);
  int rem = gid - r*(128*KP);
  int nn = rem / KP, k = rem - nn*KP;
  float v = (k < K) ? W[((size_t)r*K + k)*128 + nn] : 0.f;
  unsigned short h = f2bf(v);
  unsigned short l = f2bf(v - bf2f(h));
  Wh[gid] = (short)h;
  Wl[gid] = (short)l;
}

// ================= wa: precompute W_r @ a  (for z = x . (W a)) =================
// wa layout: [12][KP] f32; rr<6 -> a_s of rel rr; rr>=6 -> a_d of rel rr-6
template<int KP>
__global__ void k_wa(const float* __restrict__ W, const float* __restrict__ as,
                     const float* __restrict__ ad, int K, float* __restrict__ wa)
{
  int idx = blockIdx.x*256 + threadIdx.x;
  if (idx >= 12*KP) return;
  int rr = idx / KP, k = idx - rr*KP;
  int r = (rr < 6) ? rr : rr - 6;
  const float* a = ((rr < 6) ? as : ad) + (size_t)r*HH;
  float s = 0.f;
  if (k < K) {
    const float* wrow = W + ((size_t)r*K + k)*128;
    #pragma unroll 8
    for (int h = 0; h < 128; ++h) s = fmaf(wrow[h], a[h], s);
  }
  wa[idx] = s;
}

// ================= zsd: z-scores per node per relation ====================
// zsd layout: [12][N]: planes 0..5 = zs_r, 6..11 = zd_r
__global__ void k_zsd32(const short* __restrict__ xh, const short* __restrict__ xl,
                        const float* __restrict__ wa, float* __restrict__ zsd, int n)
{
  __shared__ float w[12*32];
  int tid = threadIdx.x;
  for (int i = tid; i < 12*32; i += 256) w[i] = wa[i];
  __syncthreads();
  int g = blockIdx.x*256 + tid;
  if (g >= n) return;
  float v[32];
  #pragma unroll
  for (int c = 0; c < 4; ++c) {
    uint4 vh = *(const uint4*)(xh + (size_t)g*32 + c*8);
    uint4 vl = *(const uint4*)(xl + (size_t)g*32 + c*8);
    const unsigned short* hp = (const unsigned short*)&vh;
    const unsigned short* lp = (const unsigned short*)&vl;
    #pragma unroll
    for (int j = 0; j < 8; ++j) v[c*8+j] = bf2f(hp[j]) + bf2f(lp[j]);
  }
  #pragma unroll
  for (int rr = 0; rr < 12; ++rr) {
    float d = 0.f;
    #pragma unroll
    for (int k = 0; k < 32; ++k) d = fmaf(v[k], w[rr*32+k], d);
    zsd[(size_t)rr*n + g] = d;
  }
}

__global__ void k_zsd128(const unsigned short* __restrict__ xh, const unsigned short* __restrict__ xl,
                         const float* __restrict__ wa, float* __restrict__ zsd, int n)
{
  __shared__ float w[12*128];
  int tid = threadIdx.x;
  for (int i = tid; i < 12*128; i += 256) w[i] = wa[i];
  __syncthreads();
  int gid = blockIdx.x*256 + tid;
  int g = gid >> 4, l = tid & 15;
  if (g >= n) return;
  uint4 vh = *(const uint4*)(xh + (size_t)g*128 + l*8);
  uint4 vl = *(const uint4*)(xl + (size_t)g*128 + l*8);
  const unsigned short* hp = (const unsigned short*)&vh;
  const unsigned short* lp = (const unsigned short*)&vl;
  float v[8];
  #pragma unroll
  for (int j = 0; j < 8; ++j) v[j] = bf2f(hp[j]) + bf2f(lp[j]);
  float dot[12];
  #pragma unroll
  for (int rr = 0; rr < 12; ++rr) {
    float p = 0.f;
    #pragma unroll
    for (int j = 0; j < 8; ++j) p = fmaf(v[j], w[rr*128 + l*8 + j], p);
    p += __shfl_xor(p, 1); p += __shfl_xor(p, 2);
    p += __shfl_xor(p, 4); p += __shfl_xor(p, 8);
    dot[rr] = p;
  }
  if (l < 12) zsd[(size_t)l*n + g] = dot[l];
}

// ================= fused aggregate + concat-GEMM + epilogue ====================
__device__ __forceinline__ bf16x8 ldfrag_(const short* p, int row, int kb, int KP_, int smask)
{
  int xr = row & smask;
  int s0 = (((kb)      >> 3) ^ xr) * 8 + (kb & 7);
  int s1 = (((kb + 16) >> 3) ^ xr) * 8 + (kb & 7);
  bf16x4 a = *(const bf16x4*)(p + (size_t)row*KP_ + s0);
  bf16x4 b = *(const bf16x4*)(p + (size_t)row*KP_ + s1);
  return __builtin_shufflevector(a, b, 0,1,2,3,4,5,6,7);
}

// FIN=1: write h1 bf16 hi/lo planes.  FIN=2: write f32 + fused pool score.
template<int KPR, int FIN>
__global__ __launch_bounds__(256, 3)
void k_fused(const unsigned short* __restrict__ tab,   // [n][KPR] bf16 gather table
             const float* __restrict__ zsd,            // [12][n]
             const int* __restrict__ elist,
             const int* __restrict__ off,              // [MM+1]
             const short* __restrict__ Wh, const short* __restrict__ Wl,  // [6][128][KPR]
             const float* __restrict__ bsv,
             const float* __restrict__ nw, const float* __restrict__ nb,
             unsigned short* __restrict__ Yh, unsigned short* __restrict__ Yl,
             float* __restrict__ Yf, const float* __restrict__ q,
             const int* __restrict__ batch, float* __restrict__ scores,
             unsigned* __restrict__ bmax, int n)
{
  constexpr int SLOTS = KPR/8;
  constexpr int SMASK = (SLOTS >= 8) ? 7 : (SLOTS-1);
  constexpr int ASH = 32*KPR;           // shorts per A plane
  constexpr int UB0 = (2*ASH + 128*KPR)*2;
  constexpr int UBYTES = (UB0 > 32*136*4) ? UB0 : 32*136*4;
  __shared__ __align__(16) char ldsraw[UBYTES];
  short* Ah = (short*)ldsraw;
  short* Al = Ah + ASH;
  short* Wp = Al + ASH;

  int tid = threadIdx.x;
  int gi = tid >> 4;        // 16 groups
  int l  = tid & 15;
  int gb = tid & 48;        // group base lane within wave
  int r0 = blockIdx.x * 32;

  int wid = tid >> 6, lane = tid & 63;
  int lr = lane & 15, lg = lane >> 4;
  int rt = wid >> 1;
  int c0 = (wid & 1) * 4;
  int arow = rt*16 + lr;
  f32x4 acct[4] = {{0,0,0,0},{0,0,0,0},{0,0,0,0},{0,0,0,0}};

  for (int rel = 0; rel < RR; ++rel) {
    const short* Whr = Wh + (size_t)rel*128*KPR;
    const short* Wlr = Wl + (size_t)rel*128*KPR;
    const float* zsr = zsd + (size_t)rel*n;
    const float* zdr = zsd + (size_t)(6+rel)*n;

    // ---- (a) aggregate 2 rows per 16-lane group into A hi/lo tiles ----
    #pragma unroll
    for (int rr = 0; rr < 2; ++rr) {
      int row = gi + rr*16;
      int g = r0 + row;
      float acc[8] = {0,0,0,0,0,0,0,0};
      float inv = 0.f;
      int o0 = off[(size_t)rel*NN + g];
      int deg = off[(size_t)rel*NN + g + 1] - o0;
      if (deg > 0) {
        float zdd = zdr[g];
        float m = -3.4e38f;
        for (int i = l; i < deg; i += 16) {
          float z = zsr[elist[o0+i]] + zdd;
          z = (z > 0.f) ? z : 0.2f*z;
          m = fmaxf(m, z);
        }
        m = fmaxf(m, __shfl_xor(m, 1)); m = fmaxf(m, __shfl_xor(m, 2));
        m = fmaxf(m, __shfl_xor(m, 4)); m = fmaxf(m, __shfl_xor(m, 8));
        float es = 0.f;
        for (int i = l; i < deg; i += 16) {
          float z = zsr[elist[o0+i]] + zdd;
          z = (z > 0.f) ? z : 0.2f*z;
          es += __expf(z - m);
        }
        es += __shfl_xor(es, 1); es += __shfl_xor(es, 2);
        es += __shfl_xor(es, 4); es += __shfl_xor(es, 8);
        inv = 1.f / es;
        if (KPR == 128) {
          for (int base = 0; base < deg; base += 16) {
            int i = base + l;
            float ew = 0.f; int s = 0;
            if (i < deg) {
              s = elist[o0+i];
              float z = zsr[s] + zdd;
              z = (z > 0.f) ? z : 0.2f*z;
              ew = __expf(z - m);
            }
            int cnt = min(16, deg - base);
            for (int t = 0; t < cnt; ++t) {
              float w = __shfl(ew, gb + t);
              int ss = __shfl(s, gb + t);
              uint4 v = *(const uint4*)(tab + (size_t)ss*KPR + l*8);
              acc[0] = fmaf(w, __uint_as_float(v.x << 16),         acc[0]);
              acc[1] = fmaf(w, __uint_as_float(v.x & 0xffff0000u), acc[1]);
              acc[2] = fmaf(w, __uint_as_float(v.y << 16),         acc[2]);
              acc[3] = fmaf(w, __uint_as_float(v.y & 0xffff0000u), acc[3]);
              acc[4] = fmaf(w, __uint_as_float(v.z << 16),         acc[4]);
              acc[5] = fmaf(w, __uint_as_float(v.z & 0xffff0000u), acc[5]);
              acc[6] = fmaf(w, __uint_as_float(v.w << 16),         acc[6]);
              acc[7] = fmaf(w, __uint_as_float(v.w & 0xffff0000u), acc[7]);
            }
          }
        } else {  // KPR==32: 4 edges per iter, 4 lanes per edge
          int sub = l >> 2, ch = l & 3;
          for (int base = 0; base < deg; base += 4) {
            int i = base + sub;
            float ew = 0.f; int ss = 0;
            if (i < deg) {
              ss = elist[o0+i];
              float z = zsr[ss] + zdd;
              z = (z > 0.f) ? z : 0.2f*z;
              ew = __expf(z - m);
            }
            uint4 v = *(const uint4*)(tab + (size_t)ss*KPR + ch*8);
            acc[0] = fmaf(ew, __uint_as_float(v.x << 16),         acc[0]);
            acc[1] = fmaf(ew, __uint_as_float(v.x & 0xffff0000u), acc[1]);
            acc[2] = fmaf(ew, __uint_as_float(v.y << 16),         acc[2]);
            acc[3] = fmaf(ew, __uint_as_float(v.y & 0xffff0000u), acc[3]);
            acc[4] = fmaf(ew, __uint_as_float(v.z << 16),         acc[4]);
            acc[5] = fmaf(ew, __uint_as_float(v.z & 0xffff0000u), acc[5]);
            acc[6] = fmaf(ew, __uint_as_float(v.w << 16),         acc[6]);
            acc[7] = fmaf(ew, __uint_as_float(v.w & 0xffff0000u), acc[7]);
          }
          #pragma unroll
          for (int j = 0; j < 8; ++j) {
            acc[j] += __shfl_xor(acc[j], 4);
            acc[j] += __shfl_xor(acc[j], 8);
          }
        }
      }
      // write A row (hi/lo split of f32 aggregate)
      if (KPR == 128 || l < 4) {
        int slot = (KPR == 128) ? l : l;   // slot index along k
        uint4 ph, pl;
        unsigned* php = (unsigned*)&ph; unsigned* plp = (unsigned*)&pl;
        #pragma unroll
        for (int j2 = 0; j2 < 4; ++j2) {
          float a0 = acc[2*j2]   * inv;
          float a1 = acc[2*j2+1] * inv;
          unsigned short h0 = f2bf(a0), h1 = f2bf(a1);
          php[j2] = ((unsigned)h1 << 16) | h0;
          plp[j2] = ((unsigned)f2bf(a1 - bf2f(h1)) << 16) | f2bf(a0 - bf2f(h0));
        }
        int dsl = ((slot ^ (row & SMASK))) * 8;
        *(uint4*)(Ah + row*KPR + dsl) = ph;
        *(uint4*)(Al + row*KPR + dsl) = pl;
      }
    }
    // ---- (b) stage Wh plane ----
    for (int chn = tid; chn < 128*SLOTS; chn += 256) {
      int row = chn / SLOTS, slot = chn - row*SLOTS;
      int dsl = ((slot ^ (row & SMASK))) * 8;
      *(bf16x8*)(Wp + row*KPR + dsl) = *(const bf16x8*)(Whr + (size_t)row*KPR + slot*8);
    }
    __syncthreads();
    // ---- pass 1: Ah*Wh + Al*Wh ----
    #pragma unroll
    for (int kc = 0; kc < KPR/32; ++kc) {
      int kb = kc*32 + 4*lg;
      bf16x8 ah = ldfrag_(Ah, arow, kb, KPR, SMASK);
      bf16x8 al = ldfrag_(Al, arow, kb, KPR, SMASK);
      #pragma unroll
      for (int t = 0; t < 4; ++t) {
        bf16x8 wf = ldfrag_(Wp, (c0 + t)*16 + lr, kb, KPR, SMASK);
        acct[t] = __builtin_amdgcn_mfma_f32_16x16x32_bf16(ah, wf, acct[t], 0, 0, 0);
        acct[t] = __builtin_amdgcn_mfma_f32_16x16x32_bf16(al, wf, acct[t], 0, 0, 0);
      }
    }
    __syncthreads();
    // ---- stage Wl plane ----
    for (int chn = tid; chn < 128*SLOTS; chn += 256) {
      int row = chn / SLOTS, slot = chn - row*SLOTS;
      int dsl = ((slot ^ (row & SMASK))) * 8;
      *(bf16x8*)(Wp + row*KPR + dsl) = *(const bf16x8*)(Wlr + (size_t)row*KPR + slot*8);
    }
    __syncthreads();
    // ---- pass 2: Ah*Wl ----
    #pragma unroll
    for (int kc = 0; kc < KPR/32; ++kc) {
      int kb = kc*32 + 4*lg;
      bf16x8 ah = ldfrag_(Ah, arow, kb, KPR, SMASK);
      #pragma unroll
      for (int t = 0; t < 4; ++t) {
        bf16x8 wf = ldfrag_(Wp, (c0 + t)*16 + lr, kb, KPR, SMASK);
        acct[t] = __builtin_amdgcn_mfma_f32_16x16x32_bf16(ah, wf, acct[t], 0, 0, 0);
      }
    }
    __syncthreads();
  }

  // ---- epilogue: bias + gelu -> Cs, then per-row LN ----
  float* Cs = (float*)ldsraw;   // [32][136]
  #pragma unroll
  for (int t = 0; t < 4; ++t)
    #pragma unroll
    for (int v = 0; v < 4; ++v) {
      int row = rt*16 + lg*4 + v;
      int col = (c0 + t)*16 + lr;
      float x = acct[t][v] + bsv[col];
      Cs[row*136 + col] = 0.5f*x*(1.f + erff(x*0.70710678118654752f));
    }
  __syncthreads();

  {
    int r = tid >> 3, sg = tid & 7;
    float vals[16];
    float s = 0.f;
    #pragma unroll
    for (int i = 0; i < 16; ++i) { vals[i] = Cs[r*136 + sg*16 + i]; s += vals[i]; }
    s += __shfl_xor(s, 1); s += __shfl_xor(s, 2); s += __shfl_xor(s, 4);
    float mu = s * (1.f/128.f);
    float var = 0.f;
    #pragma unroll
    for (int i = 0; i < 16; ++i) { vals[i] -= mu; var += vals[i]*vals[i]; }
    var += __shfl_xor(var, 1); var += __shfl_xor(var, 2); var += __shfl_xor(var, 4);
    float inv = 1.f / sqrtf(var*(1.f/128.f) + 1e-5f);
    int g = r0 + r;
    if (FIN == 1) {
      uint4 ph0, ph1, pl0, pl1;
      unsigned* php0 = (unsigned*)&ph0; unsigned* php1 = (unsigned*)&ph1;
      unsigned* plp0 = (unsigned*)&pl0; unsigned* plp1 = (unsigned*)&pl1;
      #pragma unroll
      for (int j2 = 0; j2 < 8; ++j2) {
        int c = sg*16 + 2*j2;
        float y0 = vals[2*j2]  *inv*nw[c]   + nb[c];
        float y1 = vals[2*j2+1]*inv*nw[c+1] + nb[c+1];
        unsigned short h0 = f2bf(y0), h1 = f2bf(y1);
        unsigned hw = ((unsigned)h1 << 16) | h0;
        unsigned lw = ((unsigned)f2bf(y1 - bf2f(h1)) << 16) | f2bf(y0 - bf2f(h0));
        if (j2 < 4) { php0[j2] = hw; plp0[j2] = lw; }
        else        { php1[j2-4] = hw; plp1[j2-4] = lw; }
      }
      *(uint4*)(Yh + (size_t)g*128 + sg*16)     = ph0;
      *(uint4*)(Yh + (size_t)g*128 + sg*16 + 8) = ph1;
      *(uint4*)(Yl + (size_t)g*128 + sg*16)     = pl0;
      *(uint4*)(Yl + (size_t)g*128 + sg*16 + 8) = pl1;
    } else {
      float sc = 0.f;
      #pragma unroll
      for (int j2 = 0; j2 < 4; ++j2) {
        float4 o;
        int c = sg*16 + j2*4;
        o.x = vals[j2*4+0]*inv*nw[c+0] + nb[c+0];
        o.y = vals[j2*4+1]*inv*nw[c+1] + nb[c+1];
        o.z = vals[j2*4+2]*inv*nw[c+2] + nb[c+2];
        o.w = vals[j2*4+3]*inv*nw[c+3] + nb[c+3];
        *(float4*)(Yf + (size_t)g*128 + c) = o;
        sc += o.x*q[c] + o.y*q[c+1] + o.z*q[c+2] + o.w*q[c+3];
      }
      sc += __shfl_xor(sc, 1); sc += __shfl_xor(sc, 2); sc += __shfl_xor(sc, 4);
      if (sg == 0) {
        scores[g] = sc;
        atomicMax(&bmax[batch[g]], fenc(sc));
      }
    }
  }
}

// ================= bias-sum =================
__global__ void k_bsum(const float* __restrict__ b, float* __restrict__ bs)
{
  int t = threadIdx.x;
  float s = 0.f;
  #pragma unroll
  for (int r = 0; r < RR; ++r) s += b[r*HH + t];
  bs[t] = s;
}

// ================= pooling =================
__global__ void k_segbounds(const int* __restrict__ batch, int* __restrict__ segst,
                            int n, int numB)
{
  int b = blockIdx.x*256 + threadIdx.x;
  if (b > numB) return;
  int lo = 0, hi = n;
  while (lo < hi) { int mid = (lo+hi) >> 1; if (batch[mid] < b) lo = mid+1; else hi = mid; }
  segst[b] = lo;
}

__global__ void k_pool(const float* __restrict__ X, const float* __restrict__ scores,
                       const int* __restrict__ segst, const unsigned* __restrict__ bmax,
                       float* __restrict__ pool, int numB)
{
  int b = blockIdx.x;
  int t = threadIdx.x;
  int s0 = segst[b], s1 = segst[b+1];
  float m = fdec(bmax[b]);
  float acc0 = 0.f, acc1 = 0.f, esum = 0.f;
  int i = s0;
  for (; i + 1 < s1; i += 2) {
    float e0 = __expf(scores[i] - m);
    float e1 = __expf(scores[i+1] - m);
    esum += e0 + e1;
    acc0 = fmaf(e0, X[(size_t)i*128 + t], acc0);
    acc1 = fmaf(e1, X[(size_t)(i+1)*128 + t], acc1);
  }
  if (i < s1) {
    float e0 = __expf(scores[i] - m);
    esum += e0;
    acc0 = fmaf(e0, X[(size_t)i*128 + t], acc0);
  }
  float inv = (s1 > s0) ? 1.f/esum : 0.f;
  pool[(size_t)b*128 + t] = (acc0 + acc1) * inv;
}

__global__ void k_outgemm(const float* __restrict__ pool, const float* __restrict__ projW,
                          const float* __restrict__ projb, float* __restrict__ out, int numB)
{
  int b = blockIdx.x;
  int j = threadIdx.x;
  __shared__ float p[128];
  p[j] = pool[(size_t)b*128 + j];
  __syncthreads();
  float acc = projb[j];
  #pragma unroll 16
  for (int k = 0; k < 128; ++k) acc = fmaf(p[k], projW[(size_t)k*128 + j], acc);
  out[(size_t)b*128 + j] = acc;
}

// ================= launcher =================
extern "C" void kernel_launch(void* const* d_in, const int* in_sizes, int n_in,
                              void* d_out, int out_size, void* d_ws, size_t ws_size,
                              hipStream_t stream)
{
  const float* x_all = (const float*)d_in[0];
  const int*   edges = (const int*)d_in[1];
  const int*   batch = (const int*)d_in[2];
  const float* pos_table = (const float*)d_in[3];
  const float* W1  = (const float*)d_in[4];
  const float* as1 = (const float*)d_in[5];
  const float* ad1 = (const float*)d_in[6];
  const float* b1  = (const float*)d_in[7];
  const float* W2  = (const float*)d_in[8];
  const float* as2 = (const float*)d_in[9];
  const float* ad2 = (const float*)d_in[10];
  const float* b2  = (const float*)d_in[11];
  const float* n1w = (const float*)d_in[12];
  const float* n1b = (const float*)d_in[13];
  const float* n2w = (const float*)d_in[14];
  const float* n2b = (const float*)d_in[15];
  const float* query = (const float*)d_in[16];
  const float* projW = (const float*)d_in[17];
  const float* projb = (const float*)d_in[18];
  float* out = (float*)d_out;
  (void)in_sizes; (void)n_in; (void)out_size; (void)ws_size;

  char* p = (char*)d_ws;
  auto alloc = [&](size_t b){ void* r = (void*)p; p += (b + 255) & ~(size_t)255; return r; };
  int*   off   = (int*)alloc((size_t)(MM+1)*sizeof(int));
  int*   elist = (int*)alloc((size_t)RR*EE*sizeof(int));
  int*   bcnt  = (int*)alloc((size_t)NBK*sizeof(int));
  int*   boff  = (int*)alloc((size_t)(NBK+1)*sizeof(int));
  int*   bcur  = (int*)alloc((size_t)NBK*sizeof(int));
  short* wtH   = (short*)alloc((size_t)RR*128*128*sizeof(short));
  short* wtL   = (short*)alloc((size_t)RR*128*128*sizeof(short));
  float* wa    = (float*)alloc((size_t)12*128*sizeof(float));
  float* zsd   = (float*)alloc((size_t)12*NN*sizeof(float));
  float* bsv   = (float*)alloc(128*sizeof(float));
  int*   segst = (int*)alloc((size_t)(BB+1)*sizeof(int));
  unsigned* bmax = (unsigned*)alloc((size_t)BB*sizeof(unsigned));
  float* pool  = (float*)alloc((size_t)BB*HH*sizeof(float));
  float* scrs  = (float*)alloc((size_t)NN*sizeof(float));
  short* x0h   = (short*)alloc((size_t)NN*32*sizeof(short));
  short* x0l   = (short*)alloc((size_t)NN*32*sizeof(short));
  unsigned short* h1h = (unsigned short*)alloc((size_t)NN*128*sizeof(short));
  unsigned short* h1l = (unsigned short*)alloc((size_t)NN*128*sizeof(short));
  float* h2    = (float*)alloc((size_t)NN*128*sizeof(float));
  unsigned* ebkt = (unsigned*)h2;   // transient: dead after k_bbuild, before h2 written

  // --- CSR build ---
  const int nch = (EE + CH - 1) / CH;
  hipMemsetAsync(bcnt, 0, (size_t)NBK*sizeof(int), stream);
  k_bcount<<<RR*nch,256,0,stream>>>(edges, bcnt);
  k_bscan<<<1,256,0,stream>>>(bcnt, boff, off);
  hipMemcpyAsync(bcur, boff, (size_t)NBK*sizeof(int), hipMemcpyDeviceToDevice, stream);
  k_binscatter<<<RR*nch,256,0,stream>>>(edges, bcur, ebkt);
  k_bbuild<<<NBK,256,0,stream>>>(ebkt, boff, off, elist);

  // --- prep ---
  k_featprep<<<ceil_div(NN*32,256),256,0,stream>>>(x_all, pos_table, x0h, x0l);
  k_segbounds<<<ceil_div(BB+1,256),256,0,stream>>>(batch, segst, NN, BB);
  hipMemsetAsync(bmax, 0, (size_t)BB*sizeof(unsigned), stream);

  // --- layer 1 (fused agg-then-project) ---
  k_wa<32><<<ceil_div(12*32,256),256,0,stream>>>(W1, as1, ad1, 21, wa);
  k_zsd32<<<ceil_div(NN,256),256,0,stream>>>(x0h, x0l, wa, zsd, NN);
  k_wprep<32><<<ceil_div(RR*128*32,256),256,0,stream>>>(W1, 21, wtH, wtL);
  k_bsum<<<1,128,0,stream>>>(b1, bsv);
  k_fused<32,1><<<NN/32,256,0,stream>>>(
      (const unsigned short*)x0h, zsd, elist, off, wtH, wtL, bsv, n1w, n1b,
      h1h, h1l, (float*)0, query, batch, scrs, bmax, NN);

  // --- layer 2 ---
  k_wa<128><<<ceil_div(12*128,256),256,0,stream>>>(W2, as2, ad2, 128, wa);
  k_zsd128<<<ceil_div(NN*16,256),256,0,stream>>>(h1h, h1l, wa, zsd, NN);
  k_wprep<128><<<ceil_div(RR*128*128,256),256,0,stream>>>(W2, 128, wtH, wtL);
  k_bsum<<<1,128,0,stream>>>(b2, bsv);
  k_fused<128,2><<<NN/32,256,0,stream>>>(
      h1h, zsd, elist, off, wtH, wtL, bsv, n2w, n2b,
      (unsigned short*)0, (unsigned short*)0, h2, query, batch, scrs, bmax, NN);

  // --- attention pooling ---
  k_pool<<<BB,128,0,stream>>>(h2, scrs, segst, bmax, pool, BB);
  k_outgemm<<<BB,128,0,stream>>>(pool, projW, projb, out, BB);
}